// Round 5
// baseline (2335.810 us; speedup 1.0000x reference)
//
#include <hip/hip_runtime.h>
#include <hip/hip_fp16.h>

#define BATCH 256
#define SEQ   2048
#define ISZ   64
#define HID   128
#define GATES 512   // 4*HID
#define KV    192   // ISZ + HID
#define KT    6     // K-tiles (of 32)
#define NBAT  2     // batch elements per block

typedef _Float16 f16x8 __attribute__((ext_vector_type(8)));
typedef float    f32x4 __attribute__((ext_vector_type(4)));

#if __has_builtin(__builtin_amdgcn_exp2f)
#define EXP2F(v) __builtin_amdgcn_exp2f(v)
#else
#define EXP2F(v) exp2f(v)
#endif
#define RCPF(v) __builtin_amdgcn_rcpf(v)

// 128 blocks x 512 threads (8 waves = 2 waves/SIMD); each block advances
// TWO independent batch elements. Weights are batch-independent, so the
// resident B-fragments (96 VGPR) serve both recurrences; per step each
// wave issues 48 MFMA in 8 independent accumulator chains plus two
// independent pointwise chains. The serial step chain (ds_read -> MFMA ->
// pointwise -> ds_write h -> barrier) is unchanged, but its stall slots
// are now filled by the sibling batch's instruction stream (round-4 was
// lockstep-serial-chain bound at 1530 cy/step with only ~480 cy of issue).
// Half the CUs idle (grid 128 < 256) -- irrelevant: latency-bound.
//
// Gate-quad ownership per wave (units [w*16,w*16+16), 4 gate N-tiles),
// broadcast-A trick => gates land in-register (C col = lane&15, rows all
// replicas). log2(e) folded into W/R/bias per gate (z-gate x2log2e) so
// every exp in the pointwise is a bare v_exp_f32. Unstabilized C,N
// recurrence (algebraically == stabilized reference, |C/N|<=1, f32-safe).
// One barrier per step; vh ping-pong.
__global__ __launch_bounds__(512, 2) void slstm_kernel(
    const float* __restrict__ x, const float* __restrict__ W,
    const float* __restrict__ R, const float* __restrict__ bias,
    float* __restrict__ out)
{
    __shared__ __align__(16) _Float16 vh[2][NBAT][KV];  // ping-pong [x_t | h]

    const int t    = threadIdx.x;
    const int lane = t & 63;
    const int w    = t >> 6;        // 0..7
    const int c16  = lane & 15;     // MFMA N-col / C-col
    const int g    = lane >> 4;     // k-group 0..3
    const int j    = w * 16 + c16;  // hidden unit this lane carries

    const float L2E = 1.4426950408889634f;
    const float sc[4] = {L2E, L2E, L2E, 2.0f * L2E};   // i, f, o, z

    // ---- preload B-fragments (shared by both batches), pre-scaled ----
    f16x8 bw[4][KT];
#pragma unroll
    for (int q = 0; q < 4; ++q) {
        const int n = q * HID + j;
#pragma unroll
        for (int kt = 0; kt < KT; ++kt) {
            f16x8 v;
#pragma unroll
            for (int e = 0; e < 8; ++e) {
                const int k = kt * 32 + g * 8 + e;
                const float f = (k < ISZ) ? W[n * ISZ + k]
                                          : R[(k - ISZ) * GATES + n];
                v[e] = (_Float16)(f * sc[q]);
            }
            bw[q][kt] = v;
        }
    }

    float bb[4];
#pragma unroll
    for (int q = 0; q < 4; ++q) bb[q] = bias[q * HID + j] * sc[q];

    // ---- two independent recurrences ----
    float C0 = 0.f, N0 = 0.f, C1 = 0.f, N1 = 0.f;

    const int b0 = 2 * blockIdx.x;
    const float* xb0 = x + (size_t)b0 * SEQ * ISZ;
    const float* xb1 = xb0 + (size_t)SEQ * ISZ;
    float* ob0 = out + (size_t)b0 * SEQ * HID;
    float* ob1 = ob0 + (size_t)SEQ * HID;

    // init buffer 0: h = 0 (both batches); wave 0 -> x of batch 0,
    // wave 1 -> x of batch 1 (lane == x index, ISZ == 64).
    if (t < NBAT * HID) vh[0][t >> 7][ISZ + (t & 127)] = (_Float16)0.f;
    const float* myxb = (w == 0) ? xb0 : xb1;
    float xreg = 0.f;
    if (w < 2) {
        vh[0][w][lane] = (_Float16)myxb[lane];
        xreg = myxb[ISZ + lane];
    }
    __syncthreads();

    for (int s = 0; s < SEQ; ++s) {
        const _Float16* v0 = vh[s & 1][0];
        const _Float16* v1 = vh[s & 1][1];
        _Float16* n0p = vh[(s + 1) & 1][0];
        _Float16* n1p = vh[(s + 1) & 1][1];

        // ---- A-fragments, both batches (broadcast into all 16 rows) ----
        const f16x8* va0 = (const f16x8*)v0;
        const f16x8* va1 = (const f16x8*)v1;
        f16x8 af0[KT], af1[KT];
#pragma unroll
        for (int kt = 0; kt < KT; ++kt) {
            af0[kt] = va0[kt * 4 + g];
            af1[kt] = va1[kt * 4 + g];
        }

        // ---- 48 MFMA, kt-outer / q-inner / batch-inner: 8 indep chains ----
        f32x4 acc0[4] = {{0.f,0.f,0.f,0.f}, {0.f,0.f,0.f,0.f},
                         {0.f,0.f,0.f,0.f}, {0.f,0.f,0.f,0.f}};
        f32x4 acc1[4] = {{0.f,0.f,0.f,0.f}, {0.f,0.f,0.f,0.f},
                         {0.f,0.f,0.f,0.f}, {0.f,0.f,0.f,0.f}};
#pragma unroll
        for (int kt = 0; kt < KT; ++kt) {
#pragma unroll
            for (int q = 0; q < 4; ++q) {
                acc0[q] = __builtin_amdgcn_mfma_f32_16x16x32_f16(
                    af0[kt], bw[q][kt], acc0[q], 0, 0, 0);
                acc1[q] = __builtin_amdgcn_mfma_f32_16x16x32_f16(
                    af1[kt], bw[q][kt], acc1[q], 0, 0, 0);
            }
        }

        // ---- pointwise, batch 0 (gates pre-scaled by log2e / 2log2e) ----
        const float gi0 = acc0[0][0] + bb[0];
        const float gf0 = acc0[1][0] + bb[1];
        const float go0 = acc0[2][0] + bb[2];
        const float gz0 = acc0[3][0] + bb[3];
        const float fp0 = RCPF(1.f + EXP2F(-gf0));       // sigmoid(f)
        const float ip0 = EXP2F(gi0);                    // exp(i)
        const float ez0 = EXP2F(gz0);                    // e^{2z}
        const float tz0 = 1.f - 2.f * RCPF(ez0 + 1.f);   // tanh(z)
        const float so0 = RCPF(1.f + EXP2F(-go0));       // sigmoid(o)
        C0 = fp0 * C0 + ip0 * tz0;
        N0 = fp0 * N0 + ip0;
        const float r0 = C0 * RCPF(N0);                  // |r| <= 1
        const float eh0 = EXP2F(2.8853900817779268f * r0);
        const float h0  = so0 * (1.f - 2.f * RCPF(eh0 + 1.f));

        // ---- pointwise, batch 1 (independent chain) ----
        const float gi1 = acc1[0][0] + bb[0];
        const float gf1 = acc1[1][0] + bb[1];
        const float go1 = acc1[2][0] + bb[2];
        const float gz1 = acc1[3][0] + bb[3];
        const float fp1 = RCPF(1.f + EXP2F(-gf1));
        const float ip1 = EXP2F(gi1);
        const float ez1 = EXP2F(gz1);
        const float tz1 = 1.f - 2.f * RCPF(ez1 + 1.f);
        const float so1 = RCPF(1.f + EXP2F(-go1));
        C1 = fp1 * C1 + ip1 * tz1;
        N1 = fp1 * N1 + ip1;
        const float r1 = C1 * RCPF(N1);
        const float eh1 = EXP2F(2.8853900817779268f * r1);
        const float h1  = so1 * (1.f - 2.f * RCPF(eh1 + 1.f));

        // ---- publish h + output stores (lanes 0-15 of each wave) ----
        if (lane < 16) {
            n0p[ISZ + j] = (_Float16)h0;
            n1p[ISZ + j] = (_Float16)h1;
            ob0[(size_t)s * HID + j] = h0;
            ob1[(size_t)s * HID + j] = h1;
        }
        // ---- publish x_{s+1} (waves 0/1), prefetch x_{s+2} ----
        if (w < 2) {
            ((w == 0) ? n0p : n1p)[lane] = (_Float16)xreg;
            xreg = (s + 2 < SEQ) ? myxb[(size_t)(s + 2) * ISZ + lane] : 0.f;
        }
        __syncthreads();   // single barrier: next step reads the new buffer
    }
}

extern "C" void kernel_launch(void* const* d_in, const int* in_sizes, int n_in,
                              void* d_out, int out_size, void* d_ws, size_t ws_size,
                              hipStream_t stream) {
    const float* x = (const float*)d_in[0];
    const float* W = (const float*)d_in[1];
    const float* R = (const float*)d_in[2];
    const float* b = (const float*)d_in[3];
    float* out = (float*)d_out;

    slstm_kernel<<<dim3(BATCH / NBAT), dim3(512), 0, stream>>>(x, W, R, b, out);
}

// Round 6
// 1423.797 us; speedup vs baseline: 1.6405x; 1.6405x over previous
//
#include <hip/hip_runtime.h>
#include <hip/hip_fp16.h>

#define BATCH 256
#define SEQ   2048
#define ISZ   64
#define HID   128
#define GATES 512   // 4*HID
#define KV    192   // ISZ + HID
#define KT    6     // K-tiles (of 32)

typedef _Float16 f16x8 __attribute__((ext_vector_type(8)));
typedef float    f32x4 __attribute__((ext_vector_type(4)));

#if __has_builtin(__builtin_amdgcn_exp2f)
#define EXP2F(v) __builtin_amdgcn_exp2f(v)
#else
#define EXP2F(v) exp2f(v)
#endif
#define RCPF(v) __builtin_amdgcn_rcpf(v)

// 256 blocks (1 batch each) x 512 threads (8 waves = 2 waves/SIMD).
// Round-4 structure: gate-quad ownership (wave w owns units [w*16,w*16+16),
// its 4 N-tiles are the 4 gate types), broadcast-A => gates land in-register
// (C col = lane&15; all rows replicas), kt-outer/q-inner MFMA (4 indep
// accumulator chains/wave), ONE barrier per step, vh ping-pong.
//
// Round-6 changes (theory: __syncthreads() emits s_waitcnt vmcnt(0) which
// drains the h global-store + x prefetch-load queue EVERY step ~300-900cy):
//   1. manual barrier: s_waitcnt lgkmcnt(0) + s_barrier + sched_barrier(0)
//      -- LDS writes visible, global ops stay in flight across steps.
//   2. output global store moved AFTER the barrier (fire-and-forget).
//   3. exp2 folding: log2(e) pre-scaled into W/R/bias (z-gate x 2log2e),
//      every exp in the pointwise is a bare v_exp_f32.
// State unstabilized (C=c*e^m, N=n*e^m): algebraically == stabilized
// reference, |C/N| <= 1, f32-safe.
__global__ __launch_bounds__(512, 2) void slstm_kernel(
    const float* __restrict__ x, const float* __restrict__ W,
    const float* __restrict__ R, const float* __restrict__ bias,
    float* __restrict__ out)
{
    __shared__ __align__(16) _Float16 vh[2][KV];   // ping-pong [x_t | h] f16

    const int t    = threadIdx.x;
    const int lane = t & 63;
    const int w    = t >> 6;        // 0..7
    const int c16  = lane & 15;     // MFMA N-col / C-col
    const int g    = lane >> 4;     // k-group 0..3
    const int j    = w * 16 + c16;  // hidden unit this lane carries

    const float L2E = 1.4426950408889634f;
    const float sc[4] = {L2E, L2E, L2E, 2.0f * L2E};   // i, f, o, z

    // ---- preload B-fragments: gate q, unit j -> column n = q*128 + j,
    //      k = kt*32 + g*8 + e (same slot rule as A; any consistent
    //      k-permutation cancels between A and B). Pre-scaled by log2e. ----
    f16x8 bw[4][KT];
#pragma unroll
    for (int q = 0; q < 4; ++q) {
        const int n = q * HID + j;
#pragma unroll
        for (int kt = 0; kt < KT; ++kt) {
            f16x8 v;
#pragma unroll
            for (int e = 0; e < 8; ++e) {
                const int k = kt * 32 + g * 8 + e;
                const float f = (k < ISZ) ? W[n * ISZ + k]
                                          : R[(k - ISZ) * GATES + n];
                v[e] = (_Float16)(f * sc[q]);
            }
            bw[q][kt] = v;
        }
    }

    float bb[4];
#pragma unroll
    for (int q = 0; q < 4; ++q) bb[q] = bias[q * HID + j] * sc[q];

    float C_st = 0.f, N_st = 0.f;

    const float* xb   = x   + (size_t)blockIdx.x * SEQ * ISZ;
    float*       outb = out + (size_t)blockIdx.x * SEQ * HID;

    // init buffer 0: h = 0, x_0; prefetch x_1
    if (t < HID) vh[0][ISZ + t] = (_Float16)0.f;
    float xreg = 0.f;
    if (t < ISZ) {
        vh[0][t] = (_Float16)xb[t];
        xreg = xb[ISZ + t];
    }
    __syncthreads();

    for (int s = 0; s < SEQ; ++s) {
        const _Float16* vcur = vh[s & 1];
        _Float16*       vnxt = vh[(s + 1) & 1];

        // ---- A-fragments: broadcast v-slice into all 16 rows ----
        const f16x8* va = (const f16x8*)vcur;
        f16x8 af[KT];
#pragma unroll
        for (int kt = 0; kt < KT; ++kt) af[kt] = va[kt * 4 + g];

        // ---- 24 MFMA, kt-outer / q-inner: 4 independent acc chains ----
        f32x4 acc[4] = {{0.f,0.f,0.f,0.f}, {0.f,0.f,0.f,0.f},
                        {0.f,0.f,0.f,0.f}, {0.f,0.f,0.f,0.f}};
#pragma unroll
        for (int kt = 0; kt < KT; ++kt) {
#pragma unroll
            for (int q = 0; q < 4; ++q)
                acc[q] = __builtin_amdgcn_mfma_f32_16x16x32_f16(
                    af[kt], bw[q][kt], acc[q], 0, 0, 0);
        }

        // ---- gates for unit j (pre-scaled by log2e / 2log2e) ----
        const float gi = acc[0][0] + bb[0];
        const float gf = acc[1][0] + bb[1];
        const float go = acc[2][0] + bb[2];
        const float gz = acc[3][0] + bb[3];

        // ---- pointwise, replicated in all lanes (no divergence) ----
        const float fp = RCPF(1.f + EXP2F(-gf));       // sigmoid(f)
        const float ip = EXP2F(gi);                    // exp(i)
        const float ez = EXP2F(gz);                    // e^{2z}
        const float tz = 1.f - 2.f * RCPF(ez + 1.f);   // tanh(z)
        const float so = RCPF(1.f + EXP2F(-go));       // sigmoid(o)

        C_st = fp * C_st + ip * tz;
        N_st = fp * N_st + ip;

        const float r  = C_st * RCPF(N_st);            // |r| <= 1
        const float eh = EXP2F(2.8853900817779268f * r);   // e^{2r}
        const float h  = so * (1.f - 2.f * RCPF(eh + 1.f));

        // ---- publish h + x_{s+1} to next buffer (LDS only) ----
        if (lane < 16) vnxt[ISZ + j] = (_Float16)h;
        if (t < ISZ) {
            vnxt[t] = (_Float16)xreg;
            xreg    = (s + 2 < SEQ) ? xb[(size_t)(s + 2) * ISZ + t] : 0.f;
        }

        // ---- barrier WITHOUT vmcnt drain: only LDS must be visible ----
        asm volatile("s_waitcnt lgkmcnt(0)" ::: "memory");
        __builtin_amdgcn_s_barrier();
        __builtin_amdgcn_sched_barrier(0);

        // ---- output store after the barrier: off the critical path,
        //      never drained inside the loop ----
        if (lane < 16) outb[(size_t)s * HID + j] = h;
    }
}

extern "C" void kernel_launch(void* const* d_in, const int* in_sizes, int n_in,
                              void* d_out, int out_size, void* d_ws, size_t ws_size,
                              hipStream_t stream) {
    const float* x = (const float*)d_in[0];
    const float* W = (const float*)d_in[1];
    const float* R = (const float*)d_in[2];
    const float* b = (const float*)d_in[3];
    float* out = (float*)d_out;

    slstm_kernel<<<dim3(BATCH), dim3(512), 0, stream>>>(x, W, R, b, out);
}

// Round 7
// 1265.787 us; speedup vs baseline: 1.8453x; 1.1248x over previous
//
#include <hip/hip_runtime.h>
#include <hip/hip_fp16.h>

#define BATCH 256
#define SEQ   2048
#define ISZ   64
#define HID   128
#define GATES 512   // 4*HID
#define WIN   16    // timesteps per px window (= MFMA M dim)
#define NWIN  (SEQ / WIN)

typedef _Float16 f16x8 __attribute__((ext_vector_type(8)));
typedef _Float16 f16x4 __attribute__((ext_vector_type(4)));
typedef float    f32x4 __attribute__((ext_vector_type(4)));

#if __has_builtin(__builtin_amdgcn_exp2f)
#define EXP2F(v) __builtin_amdgcn_exp2f(v)
#else
#define EXP2F(v) exp2f(v)
#endif
#define RCPF(v) __builtin_amdgcn_rcpf(v)

// 256 blocks (1 batch) x 512 threads (8 waves = 2 waves/SIMD).
//
// Round-7: the measured bottleneck was the matrix pipe (48 MFMA/SIMD/step
// x 19.4 cy = 931 cy of a 1550 cy step; MfmaUtil 54% == 931/1550). Fix:
// the x-projection W.x_t has no h-dependency, so 16 timesteps share one
// MFMA pass with TIMESTEPS IN THE M DIMENSION (A rows = x_s..x_s+15).
// Per wave: 8 px-MFMAs per 16-step window (amortized 0.5/step) replace
// 8 per step. The per-step GEMV keeps only the h-part (K=128, 4 K-tiles
// x 4 gate-tiles = 16 MFMA/wave). Per-SIMD matrix: 931 -> ~640 cy/step.
//
// px C-tile mapping (m89-verified, dtype-independent): col = lane&15,
// row = (lane>>4)*4 + reg. Step tau's px for col c lives in lane
// (tau>>2)*16 + c, reg tau&3 -> 4 __shfl per step.
// Gate-quad ownership unchanged: wave w owns units [w*16,w*16+16); its 4
// N-tiles are the 4 gate types; broadcast-A for the h-part => gates land
// in-register. kt-outer/q-inner (4 indep acc chains). One barrier/step
// (manual, lgkmcnt-only). exp2 folding: log2(e) pre-scaled into W/R/bias
// (z-gate x 2log2e). Unstabilized C,N recurrence (== stabilized ref).
//
// Window pipeline (x double-buffered in LDS):
//   tau=1 : wave 0 issues 4 global dwordx4 loads of x-window win+1
//   tau=6 : wave 0 cvts f32->f16, 4x ds_write_b64 into xblk[(win+1)&1]
//   tau=10: all waves read 2 A-frags from xblk[(win+1)&1], 8 px-MFMAs
//   window end: pxc <- pxn (register copy, unrolled)
__global__ __launch_bounds__(512, 2) void slstm_kernel(
    const float* __restrict__ x, const float* __restrict__ W,
    const float* __restrict__ R, const float* __restrict__ bias,
    float* __restrict__ out)
{
    __shared__ __align__(16) _Float16 vh[2][HID];         // h ping-pong
    __shared__ __align__(16) _Float16 xblk[2][WIN * ISZ]; // x windows [step][k]

    const int t    = threadIdx.x;
    const int lane = t & 63;
    const int w    = t >> 6;        // 0..7
    const int c16  = lane & 15;     // MFMA col
    const int g    = lane >> 4;     // k-group 0..3
    const int j    = w * 16 + c16;  // hidden unit this lane carries

    const float L2E = 1.4426950408889634f;
    const float sc[4] = {L2E, L2E, L2E, 2.0f * L2E};   // i, f, o, z

    // ---- B-fragments: gate q, col n = q*128 + j, k = kt*32 + g*8 + e.
    //      kt 0,1 = x-part (W); kt 2..5 = h-part (R). Pre-scaled. ----
    f16x8 bw[4][6];
#pragma unroll
    for (int q = 0; q < 4; ++q) {
        const int n = q * HID + j;
#pragma unroll
        for (int kt = 0; kt < 6; ++kt) {
            f16x8 v;
#pragma unroll
            for (int e = 0; e < 8; ++e) {
                const int k = kt * 32 + g * 8 + e;
                const float f = (k < ISZ) ? W[n * ISZ + k]
                                          : R[(k - ISZ) * GATES + n];
                v[e] = (_Float16)(f * sc[q]);
            }
            bw[q][kt] = v;
        }
    }

    float bb[4];
#pragma unroll
    for (int q = 0; q < 4; ++q) bb[q] = bias[q * HID + j] * sc[q];

    float C_st = 0.f, N_st = 0.f;

    const float* xb   = x   + (size_t)blockIdx.x * SEQ * ISZ;
    float*       outb = out + (size_t)blockIdx.x * SEQ * HID;

    // ---- prologue: h=0; stage x window 0; px for window 0 ----
    if (t < HID) vh[0][t] = (_Float16)0.f;
    if (w == 0) {
#pragma unroll
        for (int i = 0; i < 4; ++i) {
            const float4 v = ((const float4*)xb)[i * 64 + lane];
            f16x4 hv = {(_Float16)v.x, (_Float16)v.y, (_Float16)v.z, (_Float16)v.w};
            *(f16x4*)((char*)&xblk[0][0] + i * 512 + lane * 8) = hv;
        }
    }
    __syncthreads();

    f32x4 pxc[4];   // px for current window: rows = timesteps
    {
        const f16x8* xa = (const f16x8*)&xblk[0][0];
        const f16x8 xa0 = xa[c16 * 8 + 0 * 4 + g];   // A row c16, kt=0
        const f16x8 xa1 = xa[c16 * 8 + 1 * 4 + g];   // A row c16, kt=1
#pragma unroll
        for (int q = 0; q < 4; ++q) {
            f32x4 a = {0.f, 0.f, 0.f, 0.f};
            a = __builtin_amdgcn_mfma_f32_16x16x32_f16(xa0, bw[q][0], a, 0, 0, 0);
            a = __builtin_amdgcn_mfma_f32_16x16x32_f16(xa1, bw[q][1], a, 0, 0, 0);
            pxc[q] = a;
        }
    }
    f32x4 pxn[4] = {{0.f,0.f,0.f,0.f}, {0.f,0.f,0.f,0.f},
                    {0.f,0.f,0.f,0.f}, {0.f,0.f,0.f,0.f}};

    for (int win = 0; win < NWIN; ++win) {
        const bool more = (win + 1 < NWIN);
        _Float16* xstage = &xblk[(win + 1) & 1][0];
        float4 xs[4];

#pragma unroll
        for (int tau = 0; tau < WIN; ++tau) {
            const int s = win * WIN + tau;
            const _Float16* hcur = vh[tau & 1];
            _Float16*       hnxt = vh[(tau + 1) & 1];

            // ---- px extract for this step (independent; issues early) ----
            const int src = ((tau & 12) << 2) | c16;  // lane holding row tau
            const float px0 = __shfl(pxc[0][tau & 3], src);
            const float px1 = __shfl(pxc[1][tau & 3], src);
            const float px2 = __shfl(pxc[2][tau & 3], src);
            const float px3 = __shfl(pxc[3][tau & 3], src);

            // ---- h A-frags (broadcast into all 16 rows): 4 x b128 ----
            const f16x8* ha = (const f16x8*)hcur;
            f16x8 af0 = ha[0 * 4 + g];
            f16x8 af1 = ha[1 * 4 + g];
            f16x8 af2 = ha[2 * 4 + g];
            f16x8 af3 = ha[3 * 4 + g];

            // ---- 16 MFMA (h-part, K=128): kt-outer / q-inner ----
            f32x4 acc[4] = {{0.f,0.f,0.f,0.f}, {0.f,0.f,0.f,0.f},
                            {0.f,0.f,0.f,0.f}, {0.f,0.f,0.f,0.f}};
#pragma unroll
            for (int q = 0; q < 4; ++q)
                acc[q] = __builtin_amdgcn_mfma_f32_16x16x32_f16(af0, bw[q][2], acc[q], 0, 0, 0);
#pragma unroll
            for (int q = 0; q < 4; ++q)
                acc[q] = __builtin_amdgcn_mfma_f32_16x16x32_f16(af1, bw[q][3], acc[q], 0, 0, 0);
#pragma unroll
            for (int q = 0; q < 4; ++q)
                acc[q] = __builtin_amdgcn_mfma_f32_16x16x32_f16(af2, bw[q][4], acc[q], 0, 0, 0);
#pragma unroll
            for (int q = 0; q < 4; ++q)
                acc[q] = __builtin_amdgcn_mfma_f32_16x16x32_f16(af3, bw[q][5], acc[q], 0, 0, 0);

            // ---- x-window pipeline duties ----
            if (tau == 1) {
                if (w == 0 && more) {
                    const float4* xg = (const float4*)(xb + (size_t)(win + 1) * WIN * ISZ);
#pragma unroll
                    for (int i = 0; i < 4; ++i) xs[i] = xg[i * 64 + lane];
                }
            }
            if (tau == 6) {
                if (w == 0 && more) {
#pragma unroll
                    for (int i = 0; i < 4; ++i) {
                        f16x4 hv = {(_Float16)xs[i].x, (_Float16)xs[i].y,
                                    (_Float16)xs[i].z, (_Float16)xs[i].w};
                        *(f16x4*)((char*)xstage + i * 512 + lane * 8) = hv;
                    }
                }
            }
            if (tau == 10) {
                if (more) {
                    const f16x8* xa = (const f16x8*)xstage;
                    const f16x8 xa0 = xa[c16 * 8 + 0 * 4 + g];
                    const f16x8 xa1 = xa[c16 * 8 + 1 * 4 + g];
#pragma unroll
                    for (int q = 0; q < 4; ++q) {
                        f32x4 a = {0.f, 0.f, 0.f, 0.f};
                        a = __builtin_amdgcn_mfma_f32_16x16x32_f16(xa0, bw[q][0], a, 0, 0, 0);
                        a = __builtin_amdgcn_mfma_f32_16x16x32_f16(xa1, bw[q][1], a, 0, 0, 0);
                        pxn[q] = a;
                    }
                }
            }

            // ---- gates for unit j (all pre-scaled by log2e / 2log2e) ----
            const float gi = acc[0][0] + px0 + bb[0];
            const float gf = acc[1][0] + px1 + bb[1];
            const float go = acc[2][0] + px2 + bb[2];
            const float gz = acc[3][0] + px3 + bb[3];

            // ---- pointwise (replicated in all lanes; no divergence) ----
            const float fp = RCPF(1.f + EXP2F(-gf));       // sigmoid(f)
            const float ip = EXP2F(gi);                    // exp(i)
            const float ez = EXP2F(gz);                    // e^{2z}
            const float tz = 1.f - 2.f * RCPF(ez + 1.f);   // tanh(z)
            const float so = RCPF(1.f + EXP2F(-go));       // sigmoid(o)

            C_st = fp * C_st + ip * tz;
            N_st = fp * N_st + ip;

            const float r  = C_st * RCPF(N_st);            // |r| <= 1
            const float eh = EXP2F(2.8853900817779268f * r);
            const float h  = so * (1.f - 2.f * RCPF(eh + 1.f));

            // ---- publish h to next buffer (LDS only) ----
            if (lane < 16) hnxt[j] = (_Float16)h;

            // ---- barrier without vmcnt drain ----
            asm volatile("s_waitcnt lgkmcnt(0)" ::: "memory");
            __builtin_amdgcn_s_barrier();
            __builtin_amdgcn_sched_barrier(0);

            // ---- output store off the critical path ----
            if (lane < 16) outb[(size_t)s * HID + j] = h;
        }

        // ---- rotate px windows (compile-time register copy) ----
#pragma unroll
        for (int q = 0; q < 4; ++q) pxc[q] = pxn[q];
    }
}

extern "C" void kernel_launch(void* const* d_in, const int* in_sizes, int n_in,
                              void* d_out, int out_size, void* d_ws, size_t ws_size,
                              hipStream_t stream) {
    const float* x = (const float*)d_in[0];
    const float* W = (const float*)d_in[1];
    const float* R = (const float*)d_in[2];
    const float* b = (const float*)d_in[3];
    float* out = (float*)d_out;

    slstm_kernel<<<dim3(BATCH), dim3(512), 0, stream>>>(x, W, R, b, out);
}